// Round 15
// baseline (70.901 us; speedup 1.0000x reference)
//
#include <hip/hip_runtime.h>

#define NB    8
#define NH    16384
#define NL    2048
#define F_HR  64
#define F_LR  128
#define OUT_COLS 198   // 64 + 3 + 128 + 3

typedef float v2f __attribute__((ext_vector_type(2)));

// ---------------------------------------------------------------------------
// Mixed-role kernel 1: blocks [0,512) = knn (R11 structure + packed-f32
// math); blocks [512,768) = idx-independent output copy (cols 0..66 +
// zeros+batch). Co-residency: 48KB LDS x2 knn + 1 copy block = 144KB <=
// 160KB, so copy traffic rides under knn compute (proven R14: -5.5us).
// knn math: key = 0.5*|pl|^2 - <ph,pl>. v_pk_fma_f32 computes 2 candidates
// per instr; per-component fma order/rounding identical to the proven fmaf
// chain (innermost -phx*x+w, then -phy*y, then -phz*z), negation exact ->
// keys bit-identical across 10 passing rounds. Slots = (even,odd) candidate,
// slot/slice ascending + strict '<' = first-occurrence argmin.
// ---------------------------------------------------------------------------
struct PairC { v2f x, y, z, w; };       // 32 B: (x0,x1)(y0,y1)(z0,z1)(w0,w1)

__global__ __launch_bounds__(512, 4) void mixed_kernel(
    const float* __restrict__ pos_hr,   // [NB*NH, 3]
    const float* __restrict__ pos_lr,   // [NB*NL, 3]
    const float* __restrict__ x_hr,     // [NB*NH, 64]
    int* __restrict__ out_idx,          // [NB*NH]
    float* __restrict__ out)
{
    __shared__ PairC cand[NL / 2];      // 32 KiB
    __shared__ float pval[8][256];      //  8 KiB per-slice best value
    __shared__ int   pidx[8][256];      //  8 KiB per-slice best index

    if (blockIdx.x < 512) {
        // ----------------------------- knn role -----------------------------
        const int b  = blockIdx.x >> 6;     // 64 blocks per batch
        const int p0 = blockIdx.x << 8;     // first global point of this block
        const int w  = threadIdx.x >> 6;    // wave id = candidate slice
        const int l  = threadIdx.x & 63;

        const float* pl = pos_lr + (size_t)b * NL * 3;
        for (int p = threadIdx.x; p < NL / 2; p += 512) {
            const int j = p << 1;
            const float x0 = pl[j * 3 + 0], y0 = pl[j * 3 + 1], z0 = pl[j * 3 + 2];
            const float x1 = pl[j * 3 + 3], y1 = pl[j * 3 + 4], z1 = pl[j * 3 + 5];
            cand[p].x = (v2f){x0, x1};
            cand[p].y = (v2f){y0, y1};
            cand[p].z = (v2f){z0, z1};
            cand[p].w = (v2f){0.5f * ((x0 * x0 + y0 * y0) + z0 * z0),
                              0.5f * ((x1 * x1 + y1 * y1) + z1 * z1)};
        }
        __syncthreads();

        // M=4 points per lane; negated splat pairs for pk_fma
        v2f nx[4], ny[4], nz[4];
#pragma unroll
        for (int m = 0; m < 4; ++m) {
            const int pt = p0 + (m << 6) + l;
            const float phx = pos_hr[pt * 3 + 0];
            const float phy = pos_hr[pt * 3 + 1];
            const float phz = pos_hr[pt * 3 + 2];
            nx[m] = (v2f){-phx, -phx};
            ny[m] = (v2f){-phy, -phy};
            nz[m] = (v2f){-phz, -phz};
        }

        float best[4][2];
        int   bi[4][2];
#pragma unroll
        for (int m = 0; m < 4; ++m) {
            best[m][0] = 3.4e38f; best[m][1] = 3.4e38f;
            bi[m][0] = 0;         bi[m][1] = 1;
        }

        const int pbase = w << 7;           // 128 pairs per slice
#pragma unroll 2
        for (int p = 0; p < 128; ++p) {
            const v2f xp = cand[pbase + p].x;
            const v2f yp = cand[pbase + p].y;
            const v2f zp = cand[pbase + p].z;
            const v2f wp = cand[pbase + p].w;
            const int j  = (pbase + p) << 1;
#pragma unroll
            for (int m = 0; m < 4; ++m) {
                v2f t0, t1, d;
                asm("v_pk_fma_f32 %0, %1, %2, %3" : "=v"(t0) : "v"(nx[m]), "v"(xp), "v"(wp));
                asm("v_pk_fma_f32 %0, %1, %2, %3" : "=v"(t1) : "v"(ny[m]), "v"(yp), "v"(t0));
                asm("v_pk_fma_f32 %0, %1, %2, %3" : "=v"(d)  : "v"(nz[m]), "v"(zp), "v"(t1));
                if (d.x < best[m][0]) { best[m][0] = d.x; bi[m][0] = j; }     // strict <
                if (d.y < best[m][1]) { best[m][1] = d.y; bi[m][1] = j + 1; }
            }
        }

#pragma unroll
        for (int m = 0; m < 4; ++m) {
            float v = best[m][0]; int i = bi[m][0];
            if (best[m][1] < v || (best[m][1] == v && bi[m][1] < i)) {
                v = best[m][1]; i = bi[m][1];
            }
            const int ptl = (m << 6) + l;
            pval[w][ptl] = v;
            pidx[w][ptl] = i;
        }
        __syncthreads();

        const int t = threadIdx.x;
        if (t < 256) {
            float v = pval[0][t]; int i = pidx[0][t];
#pragma unroll
            for (int q = 1; q < 8; ++q) {
                const float qv = pval[q][t];
                if (qv < v) { v = qv; i = pidx[q][t]; }
            }
            out_idx[p0 + t] = b * NL + i;
        }
    } else {
        // ----------------------------- copy role ----------------------------
        const int cb = blockIdx.x - 512;    // [0,256)
        const int r0 = cb << 9;             // 512 rows per block

#pragma unroll 4
        for (int e = threadIdx.x; e < 512 * 67; e += 512) {
            const int rl  = e / 67;
            const int c   = e - rl * 67;
            const int row = r0 + rl;
            const float v = (c < F_HR) ? x_hr[(row << 6) + c]
                                       : pos_hr[row * 3 + (c - F_HR)];
            out[row * OUT_COLS + c] = v;
        }

        const int R0 = NB * NH * OUT_COLS;  // 25,952,256
        const int Z  = NB * NH * 3;         // 393,216
        const int z0 = cb << 11;
#pragma unroll
        for (int e = threadIdx.x; e < 2048; e += 512) {
            const int i = z0 + e;
            out[R0 + i] = (i < Z) ? 0.0f : (float)((i - Z) >> 14);  // NH = 2^14
        }
    }
}

// ---------------------------------------------------------------------------
// Kernel 2: slim assemble — idx-dependent cols 67..197 only (proven R14).
// P1 idx loads / P2 gathers / P3 stores; 22 iters, last one guarded.
// ---------------------------------------------------------------------------
#define GRID_B   3072
#define NTHREADS (GRID_B * 256)                 // 786,432
#define GCOLS    131
#define TOTAL_G  (NB * NH * GCOLS)              // 17,170,432
#define GROW_STEP 6003                          // 786432 / 131
#define GCOL_STEP 39                            // 786432 % 131
#define BATCH    11                             // 22 iters = 2 * 11

__global__ __launch_bounds__(256) void assemble_kernel(
    const float* __restrict__ x_lr,     // [NB*NL, 128]
    const float* __restrict__ pos_lr,   // [NB*NL, 3]
    const int* __restrict__ idx,        // [NB*NH]
    float* __restrict__ out)
{
    const int tid = blockIdx.x * blockDim.x + threadIdx.x;

    int row = tid / GCOLS;
    int col = tid - row * GCOLS;

    for (int b = 0; b < 2; ++b) {
        int   rs[BATCH], cs[BATCH], ls[BATCH];
        float vs[BATCH];

#pragma unroll
        for (int k = 0; k < BATCH; ++k) {
            const int rc = row < NB * NH ? row : NB * NH - 1;
            rs[k] = row;
            cs[k] = col;
            ls[k] = idx[rc];
            col += GCOL_STEP;
            const int carry = (col >= GCOLS) ? 1 : 0;
            col -= carry ? GCOLS : 0;
            row += GROW_STEP + carry;
        }

#pragma unroll
        for (int k = 0; k < BATCH; ++k) {
            const int c = cs[k];
            const float* a = (c < F_LR) ? x_lr   + ls[k] * F_LR + c
                                        : pos_lr + ls[k] * 3    + (c - F_LR);
            vs[k] = *a;
        }

#pragma unroll
        for (int k = 0; k < BATCH; ++k) {
            const int i = tid + (b * BATCH + k) * NTHREADS;
            if (b == 1 && k == BATCH - 1) {
                if (i < TOTAL_G) out[rs[k] * OUT_COLS + 67 + cs[k]] = vs[k];
            } else {
                out[rs[k] * OUT_COLS + 67 + cs[k]] = vs[k];
            }
        }
    }
}

extern "C" void kernel_launch(void* const* d_in, const int* in_sizes, int n_in,
                              void* d_out, int out_size, void* d_ws, size_t ws_size,
                              hipStream_t stream) {
    const float* x_hr   = (const float*)d_in[0];
    const float* pos_hr = (const float*)d_in[1];
    // d_in[2] = batch_hr (int32) — unused, batch is contiguous repeats
    const float* x_lr   = (const float*)d_in[3];
    const float* pos_lr = (const float*)d_in[4];
    // d_in[5] = batch_lr (int32) — unused

    int* idx = (int*)d_ws;                    // NB*NH ints = 512 KiB scratch

    mixed_kernel<<<dim3(768), dim3(512), 0, stream>>>(
        pos_hr, pos_lr, x_hr, idx, (float*)d_out);
    assemble_kernel<<<dim3(GRID_B), dim3(256), 0, stream>>>(
        x_lr, pos_lr, idx, (float*)d_out);
}

// Round 16
// 67.481 us; speedup vs baseline: 1.0507x; 1.0507x over previous
//
#include <hip/hip_runtime.h>

#define NB    8
#define NH    16384
#define NL    2048
#define F_HR  64
#define F_LR  128
#define OUT_COLS 198   // 64 + 3 + 128 + 3

// ---------------------------------------------------------------------------
// Mixed-role kernel: blocks [0,512) = knn, blocks [512,768) = idx-independent
// copy (proven R14 overlap: copy rides knn's idle memory pipe).
// knn (R16): value-only min scan + index rescue.
//   Phase A: wave w scans slice [256w,256w+256): d = 3-fma chain (text
//     identical to R3, bit-exact across 11 rounds), best = v_min_f32.
//     4 ALU ops/cand vs 6 with inline index tracking (-33% on dominant term).
//   Phase B: per point, min over 8 slice-minima; strict < picks LOWEST
//     winning slice on ties (= first occurrence).
//   Phase C: each wave compacts its won points (ballot+popc), then rescans
//     its 256 cands for them: lane l covers [4l,4l+4), d recomputed with the
//     SAME fmaf text -> bit-equal -> first match = lowest (lane,k) via
//     ballot/ffs. ph staged in LDS (phase A) so rescue has no global chain.
// Copy role + slim assemble: unchanged from R14 (proven).
// ---------------------------------------------------------------------------
__global__ __launch_bounds__(512, 4) void mixed_kernel(
    const float* __restrict__ pos_hr,   // [NB*NH, 3]
    const float* __restrict__ pos_lr,   // [NB*NL, 3]
    const float* __restrict__ x_hr,     // [NB*NH, 64]
    int* __restrict__ out_idx,          // [NB*NH]
    float* __restrict__ out)
{
    __shared__ float4 cand[NL];         // 32 KiB (x, y, z, 0.5*|p|^2)
    __shared__ float  pval[8][256];     //  8 KiB per-slice min value
    __shared__ float  gminL[256];       //  1 KiB global min per point
    __shared__ int    winw[256];        //  1 KiB winning slice per point
    __shared__ short  plist[8][256];    //  4 KiB per-wave compacted points
    __shared__ float  phsx[256], phsy[256], phsz[256];   // 3 KiB staged ph

    if (blockIdx.x < 512) {
        // ----------------------------- knn role -----------------------------
        const int b  = blockIdx.x >> 6;     // 64 blocks per batch
        const int p0 = blockIdx.x << 8;     // first global point of this block
        const int w  = threadIdx.x >> 6;    // wave id = candidate slice
        const int l  = threadIdx.x & 63;

        const float* pl = pos_lr + (size_t)b * NL * 3;
        for (int j = threadIdx.x; j < NL; j += 512) {
            float x = pl[j * 3 + 0];
            float y = pl[j * 3 + 1];
            float z = pl[j * 3 + 2];
            cand[j] = make_float4(x, y, z, 0.5f * ((x * x + y * y) + z * z));
        }

        float phx[4], phy[4], phz[4];
#pragma unroll
        for (int m = 0; m < 4; ++m) {
            const int pt = p0 + (m << 6) + l;
            phx[m] = pos_hr[pt * 3 + 0];
            phy[m] = pos_hr[pt * 3 + 1];
            phz[m] = pos_hr[pt * 3 + 2];
        }
        if (w == 0) {                        // stage ph for the rescue phase
#pragma unroll
            for (int m = 0; m < 4; ++m) {
                const int ptl = (m << 6) + l;
                phsx[ptl] = phx[m]; phsy[ptl] = phy[m]; phsz[ptl] = phz[m];
            }
        }
        __syncthreads();

        // Phase A: value-only scan (2 slots for ILP)
        float best0[4], best1[4];
#pragma unroll
        for (int m = 0; m < 4; ++m) { best0[m] = 3.4e38f; best1[m] = 3.4e38f; }

        const int base = w << 8;            // slice start (batch-local)
        for (int j = 0; j < 256; j += 2) {
            const float4 c0 = cand[base + j];
            const float4 c1 = cand[base + j + 1];
#pragma unroll
            for (int m = 0; m < 4; ++m) {
                float d0 = fmaf(-phz[m], c0.z, fmaf(-phy[m], c0.y, fmaf(-phx[m], c0.x, c0.w)));
                float d1 = fmaf(-phz[m], c1.z, fmaf(-phy[m], c1.y, fmaf(-phx[m], c1.x, c1.w)));
                best0[m] = fminf(best0[m], d0);
                best1[m] = fminf(best1[m], d1);
            }
        }
#pragma unroll
        for (int m = 0; m < 4; ++m)
            pval[w][(m << 6) + l] = fminf(best0[m], best1[m]);
        __syncthreads();

        // Phase B: per-point min over slices; strict < keeps lowest slice
        if (threadIdx.x < 256) {
            const int t = threadIdx.x;
            float g = pval[0][t]; int ww = 0;
#pragma unroll
            for (int q = 1; q < 8; ++q) {
                const float qv = pval[q][t];
                if (qv < g) { g = qv; ww = q; }
            }
            gminL[t] = g; winw[t] = ww;
        }
        __syncthreads();

        // Phase C: compact points this wave won, then index-rescue scan
        int cnt = 0;
#pragma unroll
        for (int m = 0; m < 4; ++m) {
            const int pt = (m << 6) + l;
            const bool pred = (winw[pt] == w);
            const unsigned long long mask = __ballot(pred);
            const int pos = __popcll(mask & ((1ull << l) - 1ull));
            if (pred) plist[w][cnt + pos] = (short)pt;
            cnt += __popcll(mask);
        }

        for (int i = 0; i < cnt; ++i) {
            const int pt = plist[w][i];
            const float qx = phsx[pt], qy = phsy[pt], qz = phsz[pt];
            const float g  = gminL[pt];
            // lane l covers cands base+4l .. base+4l+3 (ascending)
            int loc = 4;
#pragma unroll
            for (int k = 3; k >= 0; --k) {      // descending: final loc = lowest k
                const float4 c = cand[base + (l << 2) + k];
                const float d = fmaf(-qz, c.z, fmaf(-qy, c.y, fmaf(-qx, c.x, c.w)));
                if (d == g) loc = k;            // bit-exact recompute
            }
            const unsigned long long mk = __ballot(loc < 4);
            if (mk) {
                const int firstlane = __ffsll((unsigned long long)mk) - 1;
                const int locf = __shfl(loc, firstlane);
                if (l == 0)
                    out_idx[p0 + pt] = b * NL + base + (firstlane << 2) + locf;
            }
        }
    } else {
        // ----------------------------- copy role ----------------------------
        const int cb = blockIdx.x - 512;    // [0,256)
        const int r0 = cb << 9;             // 512 rows per block

#pragma unroll 4
        for (int e = threadIdx.x; e < 512 * 67; e += 512) {
            const int rl  = e / 67;
            const int c   = e - rl * 67;
            const int row = r0 + rl;
            const float v = (c < F_HR) ? x_hr[(row << 6) + c]
                                       : pos_hr[row * 3 + (c - F_HR)];
            out[row * OUT_COLS + c] = v;
        }

        const int R0 = NB * NH * OUT_COLS;  // 25,952,256
        const int Z  = NB * NH * 3;         // 393,216
        const int z0 = cb << 11;
#pragma unroll
        for (int e = threadIdx.x; e < 2048; e += 512) {
            const int i = z0 + e;
            out[R0 + i] = (i < Z) ? 0.0f : (float)((i - Z) >> 14);  // NH = 2^14
        }
    }
}

// ---------------------------------------------------------------------------
// Kernel 2: slim assemble — idx-dependent cols 67..197 only (proven R14).
// P1 idx loads / P2 gathers / P3 stores; 22 iters, last one guarded.
// ---------------------------------------------------------------------------
#define GRID_B   3072
#define NTHREADS (GRID_B * 256)                 // 786,432
#define GCOLS    131
#define TOTAL_G  (NB * NH * GCOLS)              // 17,170,432
#define GROW_STEP 6003                          // 786432 / 131
#define GCOL_STEP 39                            // 786432 % 131
#define BATCH    11                             // 22 iters = 2 * 11

__global__ __launch_bounds__(256) void assemble_kernel(
    const float* __restrict__ x_lr,     // [NB*NL, 128]
    const float* __restrict__ pos_lr,   // [NB*NL, 3]
    const int* __restrict__ idx,        // [NB*NH]
    float* __restrict__ out)
{
    const int tid = blockIdx.x * blockDim.x + threadIdx.x;

    int row = tid / GCOLS;
    int col = tid - row * GCOLS;

    for (int b = 0; b < 2; ++b) {
        int   rs[BATCH], cs[BATCH], ls[BATCH];
        float vs[BATCH];

#pragma unroll
        for (int k = 0; k < BATCH; ++k) {
            const int rc = row < NB * NH ? row : NB * NH - 1;
            rs[k] = row;
            cs[k] = col;
            ls[k] = idx[rc];
            col += GCOL_STEP;
            const int carry = (col >= GCOLS) ? 1 : 0;
            col -= carry ? GCOLS : 0;
            row += GROW_STEP + carry;
        }

#pragma unroll
        for (int k = 0; k < BATCH; ++k) {
            const int c = cs[k];
            const float* a = (c < F_LR) ? x_lr   + ls[k] * F_LR + c
                                        : pos_lr + ls[k] * 3    + (c - F_LR);
            vs[k] = *a;
        }

#pragma unroll
        for (int k = 0; k < BATCH; ++k) {
            const int i = tid + (b * BATCH + k) * NTHREADS;
            if (b == 1 && k == BATCH - 1) {
                if (i < TOTAL_G) out[rs[k] * OUT_COLS + 67 + cs[k]] = vs[k];
            } else {
                out[rs[k] * OUT_COLS + 67 + cs[k]] = vs[k];
            }
        }
    }
}

extern "C" void kernel_launch(void* const* d_in, const int* in_sizes, int n_in,
                              void* d_out, int out_size, void* d_ws, size_t ws_size,
                              hipStream_t stream) {
    const float* x_hr   = (const float*)d_in[0];
    const float* pos_hr = (const float*)d_in[1];
    // d_in[2] = batch_hr (int32) — unused, batch is contiguous repeats
    const float* x_lr   = (const float*)d_in[3];
    const float* pos_lr = (const float*)d_in[4];
    // d_in[5] = batch_lr (int32) — unused

    int* idx = (int*)d_ws;                    // NB*NH ints = 512 KiB scratch

    mixed_kernel<<<dim3(768), dim3(512), 0, stream>>>(
        pos_hr, pos_lr, x_hr, idx, (float*)d_out);
    assemble_kernel<<<dim3(GRID_B), dim3(256), 0, stream>>>(
        x_lr, pos_lr, idx, (float*)d_out);
}

// Round 17
// 54.793 us; speedup vs baseline: 1.2940x; 1.2316x over previous
//
#include <hip/hip_runtime.h>

#define NB    8
#define NH    16384
#define NL    2048
#define F_HR  64
#define F_LR  128
#define OUT_COLS 198   // 64 + 3 + 128 + 3

// ---------------------------------------------------------------------------
// Single fused kernel.
// Blocks [0,512): knn + per-block gather of idx-dependent cols 67..197.
//   Phase A: value-only min scan (R16, proven): wave w scans slice
//     [256w,256w+256), 3-fma key chain (text identical since R3, bit-exact
//     across 12 passing rounds) + v_min_f32.
//   Phase B: per-point min over 8 slice minima (strict < => lowest slice).
//   Phase C: per-wave compact + rescue scan -> winner index into s_idx (LDS).
//   Phase D (new): phase-split gather (P1 idx from LDS / P2 VMEM gathers /
//     P3 coalesced stores), e-linear decode over 256 rows x 131 cols.
//     Rationale (R16 post-mortem): assemble was a 20us serial memory tail
//     with VALU idle; fusing rides it under the grid's scan/copy phases and
//     deletes the idx global round-trip + second launch.
// Blocks [512,768): idx-independent copy: cols 0..66, zeros, batch column
//   (proven R14). 3 blocks/CU (LDS 51KB x3 = 153KB <= 160KB), 24 waves/CU.
// ---------------------------------------------------------------------------
__global__ __launch_bounds__(512, 4) void fused_kernel(
    const float* __restrict__ pos_hr,   // [NB*NH, 3]
    const float* __restrict__ pos_lr,   // [NB*NL, 3]
    const float* __restrict__ x_hr,     // [NB*NH, 64]
    const float* __restrict__ x_lr,     // [NB*NL, 128]
    float* __restrict__ out)
{
    __shared__ float4 cand[NL];         // 32 KiB (x, y, z, 0.5*|p|^2)
    __shared__ float  pval[8][256];     //  8 KiB per-slice min value
    __shared__ float  gminL[256];       //  1 KiB global min per point
    __shared__ int    winw[256];        //  1 KiB winning slice per point
    __shared__ short  plist[8][256];    //  4 KiB per-wave compacted points
    __shared__ float  phsx[256], phsy[256], phsz[256];   // 3 KiB staged ph
    __shared__ int    s_idx[256];       //  1 KiB final winner (global lr row)

    if (blockIdx.x < 512) {
        // ----------------------------- knn role -----------------------------
        const int b  = blockIdx.x >> 6;     // 64 blocks per batch
        const int p0 = blockIdx.x << 8;     // first global point of this block
        const int w  = threadIdx.x >> 6;    // wave id = candidate slice
        const int l  = threadIdx.x & 63;

        const float* pl = pos_lr + (size_t)b * NL * 3;
        for (int j = threadIdx.x; j < NL; j += 512) {
            float x = pl[j * 3 + 0];
            float y = pl[j * 3 + 1];
            float z = pl[j * 3 + 2];
            cand[j] = make_float4(x, y, z, 0.5f * ((x * x + y * y) + z * z));
        }

        float phx[4], phy[4], phz[4];
#pragma unroll
        for (int m = 0; m < 4; ++m) {
            const int pt = p0 + (m << 6) + l;
            phx[m] = pos_hr[pt * 3 + 0];
            phy[m] = pos_hr[pt * 3 + 1];
            phz[m] = pos_hr[pt * 3 + 2];
        }
        if (w == 0) {                        // stage ph for the rescue phase
#pragma unroll
            for (int m = 0; m < 4; ++m) {
                const int ptl = (m << 6) + l;
                phsx[ptl] = phx[m]; phsy[ptl] = phy[m]; phsz[ptl] = phz[m];
            }
        }
        __syncthreads();

        // Phase A: value-only scan (2 slots for ILP)
        float best0[4], best1[4];
#pragma unroll
        for (int m = 0; m < 4; ++m) { best0[m] = 3.4e38f; best1[m] = 3.4e38f; }

        const int base = w << 8;            // slice start (batch-local)
        for (int j = 0; j < 256; j += 2) {
            const float4 c0 = cand[base + j];
            const float4 c1 = cand[base + j + 1];
#pragma unroll
            for (int m = 0; m < 4; ++m) {
                float d0 = fmaf(-phz[m], c0.z, fmaf(-phy[m], c0.y, fmaf(-phx[m], c0.x, c0.w)));
                float d1 = fmaf(-phz[m], c1.z, fmaf(-phy[m], c1.y, fmaf(-phx[m], c1.x, c1.w)));
                best0[m] = fminf(best0[m], d0);
                best1[m] = fminf(best1[m], d1);
            }
        }
#pragma unroll
        for (int m = 0; m < 4; ++m)
            pval[w][(m << 6) + l] = fminf(best0[m], best1[m]);
        __syncthreads();

        // Phase B: per-point min over slices; strict < keeps lowest slice
        if (threadIdx.x < 256) {
            const int t = threadIdx.x;
            float g = pval[0][t]; int ww = 0;
#pragma unroll
            for (int q = 1; q < 8; ++q) {
                const float qv = pval[q][t];
                if (qv < g) { g = qv; ww = q; }
            }
            gminL[t] = g; winw[t] = ww;
        }
        __syncthreads();

        // Phase C: compact points this wave won, then index-rescue scan
        int cnt = 0;
#pragma unroll
        for (int m = 0; m < 4; ++m) {
            const int pt = (m << 6) + l;
            const bool pred = (winw[pt] == w);
            const unsigned long long mask = __ballot(pred);
            const int pos = __popcll(mask & ((1ull << l) - 1ull));
            if (pred) plist[w][cnt + pos] = (short)pt;
            cnt += __popcll(mask);
        }

        for (int i = 0; i < cnt; ++i) {
            const int pt = plist[w][i];
            const float qx = phsx[pt], qy = phsy[pt], qz = phsz[pt];
            const float g  = gminL[pt];
            int loc = 4;
#pragma unroll
            for (int k = 3; k >= 0; --k) {      // descending: final loc = lowest k
                const float4 c = cand[base + (l << 2) + k];
                const float d = fmaf(-qz, c.z, fmaf(-qy, c.y, fmaf(-qx, c.x, c.w)));
                if (d == g) loc = k;            // bit-exact recompute
            }
            const unsigned long long mk = __ballot(loc < 4);
            if (mk) {
                const int firstlane = __ffsll((unsigned long long)mk) - 1;
                const int locf = __shfl(loc, firstlane);
                if (l == 0)
                    s_idx[pt] = b * NL + base + (firstlane << 2) + locf;
            }
        }
        __syncthreads();

        // Phase D: gather cols 67..197 for rows p0..p0+255.
        // e-linear over 256*131 = 33536 elems; 66 = 6*11 iters; e = tid+n*512,
        // decode rl = e/131, c = e%131 incrementally (512 = 3*131 + 119).
        {
            const int tid = threadIdx.x;
            int rl = tid / 131;
            int c  = tid - rl * 131;
            for (int t = 0; t < 11; ++t) {
                int rs[6], cs[6], ls[6];
                float vs[6];
#pragma unroll
                for (int k = 0; k < 6; ++k) {
                    rs[k] = rl; cs[k] = c;
                    ls[k] = s_idx[rl < 256 ? rl : 255];
                    c += 119;
                    const int carry = (c >= 131) ? 1 : 0;
                    c -= carry ? 131 : 0;
                    rl += 3 + carry;
                }
#pragma unroll
                for (int k = 0; k < 6; ++k) {
                    const int cc = cs[k];
                    const float* a = (cc < F_LR) ? x_lr   + ls[k] * F_LR + cc
                                                 : pos_lr + ls[k] * 3    + (cc - F_LR);
                    vs[k] = *a;
                }
#pragma unroll
                for (int k = 0; k < 6; ++k) {
                    if (t == 10 && k == 5 && tid + 33280 >= 33536) continue;  // guard
                    out[(size_t)(p0 + rs[k]) * OUT_COLS + 67 + cs[k]] = vs[k];
                }
            }
        }
    } else {
        // ----------------------------- copy role ----------------------------
        const int cb = blockIdx.x - 512;    // [0,256)
        const int r0 = cb << 9;             // 512 rows per block

#pragma unroll 4
        for (int e = threadIdx.x; e < 512 * 67; e += 512) {
            const int rl  = e / 67;
            const int c   = e - rl * 67;
            const int row = r0 + rl;
            const float v = (c < F_HR) ? x_hr[(row << 6) + c]
                                       : pos_hr[row * 3 + (c - F_HR)];
            out[row * OUT_COLS + c] = v;
        }

        const int R0 = NB * NH * OUT_COLS;  // 25,952,256
        const int Z  = NB * NH * 3;         // 393,216
        const int z0 = cb << 11;
#pragma unroll
        for (int e = threadIdx.x; e < 2048; e += 512) {
            const int i = z0 + e;
            out[R0 + i] = (i < Z) ? 0.0f : (float)((i - Z) >> 14);  // NH = 2^14
        }
    }
}

extern "C" void kernel_launch(void* const* d_in, const int* in_sizes, int n_in,
                              void* d_out, int out_size, void* d_ws, size_t ws_size,
                              hipStream_t stream) {
    const float* x_hr   = (const float*)d_in[0];
    const float* pos_hr = (const float*)d_in[1];
    // d_in[2] = batch_hr (int32) — unused, batch is contiguous repeats
    const float* x_lr   = (const float*)d_in[3];
    const float* pos_lr = (const float*)d_in[4];
    // d_in[5] = batch_lr (int32) — unused

    fused_kernel<<<dim3(768), dim3(512), 0, stream>>>(
        pos_hr, pos_lr, x_hr, x_lr, (float*)d_out);
}